// Round 1
// baseline (804.303 us; speedup 1.0000x reference)
//
#include <hip/hip_runtime.h>

#define B_ 256
#define C_ 64
#define M_ 4096
#define SLICES 8
#define MSLICE (M_ / SLICES) // 512

// ---------------------------------------------------------------------------
// Kernel 1: partial Gram (64x64) + partial channel sums per (batch, m-slice).
// One wave (64 threads) per block, 8x8 register tile per thread -> 1 B/FMA LDS.
// ---------------------------------------------------------------------------
__global__ __launch_bounds__(64) void k_gram(const float* __restrict__ x,
                                             float* __restrict__ Gp,
                                             float* __restrict__ Mp) {
    const int b = blockIdx.x;
    const int s = blockIdx.y;
    const int t = threadIdx.x;
    const int tc = t >> 3, td = t & 7;

    __shared__ float Xt[32][68]; // [m-local][c], padded stride 68
    __shared__ float ms[64][9];  // mean partials

    float acc[8][8];
#pragma unroll
    for (int i = 0; i < 8; ++i)
#pragma unroll
        for (int j = 0; j < 8; ++j) acc[i][j] = 0.f;
    float msum[8] = {0, 0, 0, 0, 0, 0, 0, 0};

    const float* xb = x + (size_t)b * C_ * M_ + s * MSLICE;

    for (int stage = 0; stage < MSLICE / 32; ++stage) {
        const float* xs = xb + stage * 32;
        __syncthreads(); // protect Xt from previous iteration's readers
#pragma unroll
        for (int k = 0; k < 8; ++k) {
            int f4 = t + 64 * k;      // 0..511 unique
            int c = f4 >> 3;          // 0..63
            int m4 = f4 & 7;          // 0..7  (== t&7, invariant per thread)
            float4 v = *(const float4*)(xs + (size_t)c * M_ + m4 * 4);
            msum[k] += v.x + v.y + v.z + v.w; // channel c = tc + 8k
            Xt[m4 * 4 + 0][c] = v.x;
            Xt[m4 * 4 + 1][c] = v.y;
            Xt[m4 * 4 + 2][c] = v.z;
            Xt[m4 * 4 + 3][c] = v.w;
        }
        __syncthreads();
#pragma unroll 4
        for (int m = 0; m < 32; ++m) {
            float a[8], bb[8];
            *(float4*)&a[0]  = *(const float4*)&Xt[m][tc * 8];
            *(float4*)&a[4]  = *(const float4*)&Xt[m][tc * 8 + 4];
            *(float4*)&bb[0] = *(const float4*)&Xt[m][td * 8];
            *(float4*)&bb[4] = *(const float4*)&Xt[m][td * 8 + 4];
#pragma unroll
            for (int i = 0; i < 8; ++i)
#pragma unroll
                for (int j = 0; j < 8; ++j)
                    acc[i][j] = fmaf(a[i], bb[j], acc[i][j]);
        }
    }

    // store partial gram: G[c][d], c = tc*8+i, d = td*8+j
    float* gp = Gp + ((size_t)(b * SLICES + s)) * 4096;
#pragma unroll
    for (int i = 0; i < 8; ++i) {
        *(float4*)&gp[(tc * 8 + i) * 64 + td * 8 + 0] =
            make_float4(acc[i][0], acc[i][1], acc[i][2], acc[i][3]);
        *(float4*)&gp[(tc * 8 + i) * 64 + td * 8 + 4] =
            make_float4(acc[i][4], acc[i][5], acc[i][6], acc[i][7]);
    }
    // mean partials: thread t holds partial for channel (tc + 8k), m-lane td
#pragma unroll
    for (int k = 0; k < 8; ++k) ms[tc + 8 * k][td] = msum[k];
    __syncthreads();
    {
        float ssum = 0.f;
#pragma unroll
        for (int l = 0; l < 8; ++l) ssum += ms[t][l];
        Mp[(size_t)(b * SLICES + s) * 64 + t] = ssum;
    }
}

// ---------------------------------------------------------------------------
// Kernel 2: per batch — reduce partials, cov, RBLW shrinkage, chol(cov)=R R^T,
// Xinv = R^-1 (forward subst), A = Xinv^T Xinv = inv(cov), chol(A) = L.
// Emits L (lower, zeroed upper) and wmu[c] = sum_d L[d][c]*mu[d].
// ---------------------------------------------------------------------------
__global__ __launch_bounds__(256) void k_solve(const float* __restrict__ Gp,
                                               const float* __restrict__ Mp,
                                               float* __restrict__ Lg,
                                               float* __restrict__ wmug) {
    const int b = blockIdx.x;
    const int t = threadIdx.x;
    __shared__ float C[64][65];
    __shared__ float X[64][65]; // X[c][i] = (R^-1)[i][c]
    __shared__ float A[64][65];
    __shared__ float mu[64];
    __shared__ float red[256];
    __shared__ float sc[4]; // 0: trace, 1: second_trace, 2: rho

    // reduce gram partials
    for (int idx = t; idx < 4096; idx += 256) {
        float ssum = 0.f;
        for (int sl = 0; sl < SLICES; ++sl)
            ssum += Gp[((size_t)(b * SLICES + sl)) * 4096 + idx];
        C[idx >> 6][idx & 63] = ssum;
    }
    if (t < 64) {
        float ssum = 0.f;
        for (int sl = 0; sl < SLICES; ++sl)
            ssum += Mp[(size_t)(b * SLICES + sl) * 64 + t];
        mu[t] = ssum * (1.0f / M_);
    }
    __syncthreads();
    // cov = G/M - mu mu^T
    for (int idx = t; idx < 4096; idx += 256) {
        int i = idx >> 6, j = idx & 63;
        C[i][j] = C[i][j] * (1.0f / M_) - mu[i] * mu[j];
    }
    __syncthreads();
    // trace and second trace
    float trp = 0.f, stp = 0.f;
    for (int idx = t; idx < 4096; idx += 256) {
        int i = idx >> 6, j = idx & 63;
        float v = C[i][j];
        stp += v * C[j][i];
        if (i == j) trp += v;
    }
    red[t] = stp;
    __syncthreads();
    for (int off = 128; off > 0; off >>= 1) {
        if (t < off) red[t] += red[t + off];
        __syncthreads();
    }
    if (t == 0) sc[1] = red[0];
    __syncthreads();
    red[t] = trp;
    __syncthreads();
    for (int off = 128; off > 0; off >>= 1) {
        if (t < off) red[t] += red[t + off];
        __syncthreads();
    }
    if (t == 0) {
        float tr = red[0], st = sc[1];
        const float n = (float)M_, p = 64.f;
        float num = (n - 2.f) / n * st + tr * tr;
        float den = (n + 2.f) * (st - tr * tr / p);
        float rho = fminf(num / den, 1.0f);
        sc[0] = tr;
        sc[2] = rho;
    }
    __syncthreads();
    {
        float rho = sc[2], tr = sc[0];
        float diagadd = rho * tr / 64.f;
        for (int idx = t; idx < 4096; idx += 256) {
            int i = idx >> 6, j = idx & 63;
            float v = (1.f - rho) * C[i][j];
            if (i == j) v += diagadd;
            C[i][j] = v;
        }
    }
    __syncthreads();
    // Cholesky in place (lower): C := R with cov = R R^T
    for (int k = 0; k < 64; ++k) {
        if (t == 0) C[k][k] = sqrtf(C[k][k]);
        __syncthreads();
        float dinv = 1.0f / C[k][k];
        for (int i = k + 1 + t; i < 64; i += 256) C[i][k] *= dinv;
        __syncthreads();
        for (int idx = t; idx < 4096; idx += 256) {
            int i = idx >> 6, j = idx & 63;
            if (j > k && i >= j) C[i][j] -= C[i][k] * C[j][k];
        }
        __syncthreads();
    }
    // forward substitution: lane c solves R * X[:,c] = e_c (zeros above c fall out)
    if (t < 64) {
        const int c = t;
        for (int i = 0; i < 64; ++i) {
            float ssum = (i == c) ? 1.0f : 0.0f;
            for (int j = 0; j < i; ++j) ssum -= C[i][j] * X[c][j];
            X[c][i] = ssum / C[i][i];
        }
    }
    __syncthreads();
    // A = Xinv^T Xinv  (X[i][k] = 0 for k < i, so full-K sum is exact)
    for (int idx = t; idx < 4096; idx += 256) {
        int i = idx >> 6, j = idx & 63;
        float ssum = 0.f;
#pragma unroll 8
        for (int k = 0; k < 64; ++k) ssum += X[i][k] * X[j][k];
        A[i][j] = ssum;
    }
    __syncthreads();
    // Cholesky of A -> L (lower)
    for (int k = 0; k < 64; ++k) {
        if (t == 0) A[k][k] = sqrtf(A[k][k]);
        __syncthreads();
        float dinv = 1.0f / A[k][k];
        for (int i = k + 1 + t; i < 64; i += 256) A[i][k] *= dinv;
        __syncthreads();
        for (int idx = t; idx < 4096; idx += 256) {
            int i = idx >> 6, j = idx & 63;
            if (j > k && i >= j) A[i][j] -= A[i][k] * A[j][k];
        }
        __syncthreads();
    }
    // write L (row-major [d][c], upper zeroed) and wmu
    for (int idx = t; idx < 4096; idx += 256) {
        int d = idx >> 6, c = idx & 63;
        Lg[(size_t)b * 4096 + idx] = (c <= d) ? A[d][c] : 0.f;
    }
    if (t < 64) {
        float ssum = 0.f;
        for (int d = t; d < 64; ++d) ssum += A[d][t] * mu[d];
        wmug[b * 64 + t] = ssum;
    }
}

// ---------------------------------------------------------------------------
// Kernel 3: Z[c][m] = sum_d L[d][c] * x[d][m] - wmu[c]
// 128 threads, 8c x 4m register tile, 64c x 64m subtiles, 8 subtiles/block.
// ---------------------------------------------------------------------------
__global__ __launch_bounds__(128) void k_apply(const float* __restrict__ x,
                                               const float* __restrict__ Lg,
                                               const float* __restrict__ wmug,
                                               float* __restrict__ out) {
    const int b = blockIdx.x;
    const int s = blockIdx.y;
    const int t = threadIdx.x;
    const int tc = t >> 4, tm = t & 15;

    __shared__ float Lt[64][68]; // Lt[d][c] = L[d][c]
    __shared__ float Xm[64][68]; // Xm[d][m-local]
    __shared__ float wsh[64];

#pragma unroll
    for (int k = 0; k < 8; ++k) {
        int f4 = t + 128 * k; // 0..1023
        int d = f4 >> 4, c4 = f4 & 15;
        float4 v = *(const float4*)(Lg + (size_t)b * 4096 + d * 64 + c4 * 4);
        *(float4*)&Lt[d][c4 * 4] = v;
    }
    if (t < 64) wsh[t] = wmug[b * 64 + t];

    const float* xb = x + (size_t)b * C_ * M_;
    float* ob = out + (size_t)b * C_ * M_;

    for (int sub = 0; sub < 8; ++sub) {
        const int m0 = s * MSLICE + sub * 64;
        __syncthreads(); // protect Xm (and publish Lt on first iter)
#pragma unroll
        for (int k = 0; k < 8; ++k) {
            int f4 = t + 128 * k;
            int d = f4 >> 4, m4 = f4 & 15;
            float4 v = *(const float4*)(xb + (size_t)d * M_ + m0 + m4 * 4);
            *(float4*)&Xm[d][m4 * 4] = v;
        }
        __syncthreads();
        float acc[8][4];
#pragma unroll
        for (int i = 0; i < 8; ++i)
            acc[i][0] = acc[i][1] = acc[i][2] = acc[i][3] = 0.f;
#pragma unroll 4
        for (int d = 0; d < 64; ++d) {
            float a[8];
            *(float4*)&a[0] = *(const float4*)&Lt[d][tc * 8];
            *(float4*)&a[4] = *(const float4*)&Lt[d][tc * 8 + 4];
            float4 bv = *(const float4*)&Xm[d][tm * 4];
#pragma unroll
            for (int i = 0; i < 8; ++i) {
                acc[i][0] = fmaf(a[i], bv.x, acc[i][0]);
                acc[i][1] = fmaf(a[i], bv.y, acc[i][1]);
                acc[i][2] = fmaf(a[i], bv.z, acc[i][2]);
                acc[i][3] = fmaf(a[i], bv.w, acc[i][3]);
            }
        }
#pragma unroll
        for (int i = 0; i < 8; ++i) {
            int c = tc * 8 + i;
            float w = wsh[c];
            float4 o = make_float4(acc[i][0] - w, acc[i][1] - w,
                                   acc[i][2] - w, acc[i][3] - w);
            *(float4*)(ob + (size_t)c * M_ + m0 + tm * 4) = o;
        }
    }
}

// ---------------------------------------------------------------------------
extern "C" void kernel_launch(void* const* d_in, const int* in_sizes, int n_in,
                              void* d_out, int out_size, void* d_ws, size_t ws_size,
                              hipStream_t stream) {
    const float* x = (const float*)d_in[0];
    float* out = (float*)d_out;

    const size_t gp_elems = (size_t)B_ * SLICES * 4096; // 8.39M floats
    const size_t mp_elems = (size_t)B_ * SLICES * 64;   // 131K floats
    const size_t lg_elems = (size_t)B_ * 4096;          // 1.05M floats
    const size_t wm_elems = (size_t)B_ * 64;

    float *Gp, *Mp, *Lg, *Wm;
    const size_t need_all = (gp_elems + mp_elems + lg_elems + wm_elems) * 4;
    if (ws_size >= need_all) {
        float* w = (float*)d_ws;
        Gp = w;
        Mp = Gp + gp_elems;
        Lg = Mp + mp_elems;
        Wm = Lg + lg_elems;
    } else {
        // partial Gram/means live in d_out (consumed by k_solve before k_apply
        // overwrites d_out); only L and W*mu (4.2 MB) need real scratch.
        Gp = out;
        Mp = Gp + gp_elems;
        float* w = (float*)d_ws;
        Lg = w;
        Wm = Lg + lg_elems;
    }

    k_gram<<<dim3(B_, SLICES), 64, 0, stream>>>(x, Gp, Mp);
    k_solve<<<dim3(B_), 256, 0, stream>>>(Gp, Mp, Lg, Wm);
    k_apply<<<dim3(B_, SLICES), 128, 0, stream>>>(x, Lg, Wm, out);
}

// Round 2
// 789.500 us; speedup vs baseline: 1.0187x; 1.0187x over previous
//
#include <hip/hip_runtime.h>

#define B_ 256
#define C_ 64
#define M_ 4096

// One block per batch (256 blocks == 256 CUs), 256 threads (4 waves).
// Phase 1: Gram via per-wave 8x8 register tiles over M/4 each, LDS staging
//          double-buffered through registers.
// Phase 2: cross-wave reduce of 4 partial Grams (LDS), mean, cov.
// Phase 3: Rao-Blackwell LW shrinkage scalars + blend.
// Phase 4: reverse (UL) Cholesky cov = U U^T (U upper), then W = U^-1 by
//          lane-private back-substitution.  Key identity:
//          L = chol(inv(cov)) (lower)  ==>  L^T = U^-1 = W, so Z = W x_cnt.
// Phase 5: Z = W x - (W mu), chunked over M with register-prefetch staging.
__global__ __launch_bounds__(256) void k_fused(const float* __restrict__ x,
                                               float* __restrict__ out) {
    const int b = blockIdx.x;
    const int t = threadIdx.x;
    const int w = t >> 6;   // wave 0..3
    const int l = t & 63;   // lane

    __shared__ float St[64][68];   // staging / reduce region / Xm chunk
    __shared__ float Cw[64][68];   // cov -> U -> W^T (transposed W)
    __shared__ float Ww[64][68];   // reduce region -> W (upper)
    __shared__ float ms[64][17];   // mean partials
    __shared__ float mu[64];
    __shared__ float red[256];
    __shared__ float ucol[64];
    __shared__ float wmu[64];
    __shared__ float sc[4];        // 0: trace, 1: second_trace, 2: rho

    const float* xb = x + (size_t)b * (C_ * M_);
    float* ob = out + (size_t)b * (C_ * M_);

    // ---------------- Phase 1: per-wave partial Gram ----------------
    const int tc = l >> 3, td = l & 7;   // 8x8 tile coords
    const int cl = l >> 2;               // staging channel sub-index 0..15
    const int m4 = l & 3;                // staging m sub-index 0..3

    float acc[8][8];
#pragma unroll
    for (int i = 0; i < 8; ++i)
#pragma unroll
        for (int j = 0; j < 8; ++j) acc[i][j] = 0.f;
    float msum[4] = {0.f, 0.f, 0.f, 0.f};

    const int mbase = w * 1024;
    float4 r[4];
#pragma unroll
    for (int k = 0; k < 4; ++k)
        r[k] = *(const float4*)(xb + (size_t)(cl + 16 * k) * M_ + mbase + m4 * 4);

    for (int s = 0; s < 64; ++s) {
        __syncthreads();  // previous stage's readers done
#pragma unroll
        for (int k = 0; k < 4; ++k) {
            float4 v = r[k];
            msum[k] += v.x + v.y + v.z + v.w;
            const int row = w * 16 + m4 * 4;
            const int c = cl + 16 * k;
            St[row + 0][c] = v.x;
            St[row + 1][c] = v.y;
            St[row + 2][c] = v.z;
            St[row + 3][c] = v.w;
        }
        if (s < 63) {
#pragma unroll
            for (int k = 0; k < 4; ++k)
                r[k] = *(const float4*)(xb + (size_t)(cl + 16 * k) * M_ +
                                        mbase + (s + 1) * 16 + m4 * 4);
        }
        __syncthreads();  // stage visible
#pragma unroll 2
        for (int m = 0; m < 16; ++m) {
            float a[8], bb[8];
            *(float4*)&a[0]  = *(const float4*)&St[w * 16 + m][tc * 8];
            *(float4*)&a[4]  = *(const float4*)&St[w * 16 + m][tc * 8 + 4];
            *(float4*)&bb[0] = *(const float4*)&St[w * 16 + m][td * 8];
            *(float4*)&bb[4] = *(const float4*)&St[w * 16 + m][td * 8 + 4];
#pragma unroll
            for (int i = 0; i < 8; ++i)
#pragma unroll
                for (int j = 0; j < 8; ++j)
                    acc[i][j] = fmaf(a[i], bb[j], acc[i][j]);
        }
    }
#pragma unroll
    for (int k = 0; k < 4; ++k) ms[cl + 16 * k][w * 4 + m4] = msum[k];
    __syncthreads();

    // ---------------- Phase 2: cross-wave reduce ----------------
    if (w == 1) {
#pragma unroll
        for (int i = 0; i < 8; ++i) {
            *(float4*)&Ww[tc * 8 + i][td * 8]     = make_float4(acc[i][0], acc[i][1], acc[i][2], acc[i][3]);
            *(float4*)&Ww[tc * 8 + i][td * 8 + 4] = make_float4(acc[i][4], acc[i][5], acc[i][6], acc[i][7]);
        }
        float s = 0.f;
#pragma unroll
        for (int q = 0; q < 16; ++q) s += ms[l][q];
        mu[l] = s * (1.0f / M_);
    } else if (w == 2) {
#pragma unroll
        for (int i = 0; i < 8; ++i) {
            *(float4*)&Cw[tc * 8 + i][td * 8]     = make_float4(acc[i][0], acc[i][1], acc[i][2], acc[i][3]);
            *(float4*)&Cw[tc * 8 + i][td * 8 + 4] = make_float4(acc[i][4], acc[i][5], acc[i][6], acc[i][7]);
        }
    } else if (w == 3) {
#pragma unroll
        for (int i = 0; i < 8; ++i) {
            *(float4*)&St[tc * 8 + i][td * 8]     = make_float4(acc[i][0], acc[i][1], acc[i][2], acc[i][3]);
            *(float4*)&St[tc * 8 + i][td * 8 + 4] = make_float4(acc[i][4], acc[i][5], acc[i][6], acc[i][7]);
        }
    }
    __syncthreads();
    if (w == 0) {
#pragma unroll
        for (int i = 0; i < 8; ++i) {
            float4 p0 = *(const float4*)&Ww[tc * 8 + i][td * 8];
            float4 p1 = *(const float4*)&Cw[tc * 8 + i][td * 8];
            float4 p2 = *(const float4*)&St[tc * 8 + i][td * 8];
            float4 q0 = *(const float4*)&Ww[tc * 8 + i][td * 8 + 4];
            float4 q1 = *(const float4*)&Cw[tc * 8 + i][td * 8 + 4];
            float4 q2 = *(const float4*)&St[tc * 8 + i][td * 8 + 4];
            float4 lo = make_float4(acc[i][0] + p0.x + p1.x + p2.x,
                                    acc[i][1] + p0.y + p1.y + p2.y,
                                    acc[i][2] + p0.z + p1.z + p2.z,
                                    acc[i][3] + p0.w + p1.w + p2.w);
            float4 hi = make_float4(acc[i][4] + q0.x + q1.x + q2.x,
                                    acc[i][5] + q0.y + q1.y + q2.y,
                                    acc[i][6] + q0.z + q1.z + q2.z,
                                    acc[i][7] + q0.w + q1.w + q2.w);
            *(float4*)&Cw[tc * 8 + i][td * 8]     = lo;
            *(float4*)&Cw[tc * 8 + i][td * 8 + 4] = hi;
        }
    }
    __syncthreads();
    // cov = G/M - mu mu^T
    for (int idx = t; idx < 4096; idx += 256) {
        int i = idx >> 6, j = idx & 63;
        Cw[i][j] = Cw[i][j] * (1.0f / M_) - mu[i] * mu[j];
    }
    __syncthreads();

    // ---------------- Phase 3: shrinkage ----------------
    {
        float trp = 0.f, stp = 0.f;
        for (int idx = t; idx < 4096; idx += 256) {
            int i = idx >> 6, j = idx & 63;
            float v = Cw[i][j];
            stp = fmaf(v, Cw[j][i], stp);
            if (i == j) trp += v;
        }
        red[t] = stp;
        __syncthreads();
        for (int off = 128; off > 0; off >>= 1) {
            if (t < off) red[t] += red[t + off];
            __syncthreads();
        }
        if (t == 0) sc[1] = red[0];
        __syncthreads();
        red[t] = trp;
        __syncthreads();
        for (int off = 128; off > 0; off >>= 1) {
            if (t < off) red[t] += red[t + off];
            __syncthreads();
        }
        if (t == 0) {
            float tr = red[0], st = sc[1];
            const float n = (float)M_, p = 64.f;
            float num = (n - 2.f) / n * st + tr * tr;
            float den = (n + 2.f) * (st - tr * tr / p);
            float rho = fminf(num / den, 1.0f);
            sc[0] = tr;
            sc[2] = rho;
        }
        __syncthreads();
        float rho = sc[2], tr = sc[0];
        float dadd = rho * tr * (1.0f / 64.0f);
        for (int idx = t; idx < 4096; idx += 256) {
            int i = idx >> 6, j = idx & 63;
            float v = (1.f - rho) * Cw[i][j];
            if (i == j) v += dadd;
            Cw[i][j] = v;
        }
    }

    // ---------------- Phase 4a: UL Cholesky (cov = U U^T, U upper) --------
    for (int k = 63; k >= 0; --k) {
        __syncthreads();  // prior updates visible
        float dkk = sqrtf(Cw[k][k]);
        float dinv = 1.0f / dkk;
        for (int i = t; i < k; i += 256) ucol[i] = Cw[i][k] * dinv;
        if (t == 0) ucol[k] = dkk;
        __syncthreads();
        const int nel = (k * (k + 1)) >> 1;
        for (int e = t; e < nel; e += 256) {
            int j = (int)((sqrtf((float)(8 * e + 1)) - 1.0f) * 0.5f);
            if (e < ((j * (j + 1)) >> 1)) --j;
            else if (e >= (((j + 1) * (j + 2)) >> 1)) ++j;
            int i = e - ((j * (j + 1)) >> 1);
            Cw[i][j] = fmaf(-ucol[i], ucol[j], Cw[i][j]);
        }
        for (int i = t; i <= k; i += 256) Cw[i][k] = ucol[i];
    }
    __syncthreads();

    // ---------------- Phase 4b: W = U^-1 (upper), lane-private columns ----
    if (t < 64) {
        const int j = t;
        Ww[j][j] = 1.0f / Cw[j][j];
        for (int i = j - 1; i >= 0; --i) {
            float s0 = 0.f, s1 = 0.f;
            int lq = i + 1;
            for (; lq + 1 <= j; lq += 2) {
                s0 = fmaf(Cw[i][lq], Ww[lq][j], s0);
                s1 = fmaf(Cw[i][lq + 1], Ww[lq + 1][j], s1);
            }
            if (lq <= j) s0 = fmaf(Cw[i][lq], Ww[lq][j], s0);
            Ww[i][j] = -(s0 + s1) / Cw[i][i];
        }
    }
    __syncthreads();
    // wmu[c] = sum_d W[c][d] mu[d]; transpose W into Cw: Cw[d][c] = W[c][d]
    if (t < 64) {
        float s = 0.f;
        for (int d = t; d < 64; ++d) s = fmaf(Ww[t][d], mu[d], s);
        wmu[t] = s;
    }
    for (int idx = t; idx < 4096; idx += 256) {
        int d = idx >> 6, c = idx & 63;
        Cw[d][c] = (d >= c) ? Ww[c][d] : 0.f;
    }

    // ---------------- Phase 5: Z = W x - wmu ----------------
    const int tc5 = t >> 5;   // 0..7 (c-group)
    const int tm5 = t & 31;   // 0..31 (m-pair)
    const int cld = t >> 4;   // staging: 0..15
    const int m45 = t & 15;   // staging: 0..15
    const int d0 = w * 16;    // wave-uniform triangular skip

    float4 r2[4];
#pragma unroll
    for (int k = 0; k < 4; ++k)
        r2[k] = *(const float4*)(xb + (size_t)(cld + 16 * k) * M_ + m45 * 4);

    for (int ch = 0; ch < 64; ++ch) {
        const int m0 = ch * 64;
        __syncthreads();  // (first iter: also covers transpose) prev readers done
#pragma unroll
        for (int k = 0; k < 4; ++k)
            *(float4*)&St[cld + 16 * k][m45 * 4] = r2[k];
        if (ch < 63) {
#pragma unroll
            for (int k = 0; k < 4; ++k)
                r2[k] = *(const float4*)(xb + (size_t)(cld + 16 * k) * M_ +
                                         m0 + 64 + m45 * 4);
        }
        __syncthreads();
        float a2[8][2];
#pragma unroll
        for (int i = 0; i < 8; ++i) a2[i][0] = a2[i][1] = 0.f;
        for (int d = d0; d < 64; ++d) {
            float a[8];
            *(float4*)&a[0] = *(const float4*)&Cw[d][tc5 * 8];
            *(float4*)&a[4] = *(const float4*)&Cw[d][tc5 * 8 + 4];
            float2 bv = *(const float2*)&St[d][tm5 * 2];
#pragma unroll
            for (int i = 0; i < 8; ++i) {
                a2[i][0] = fmaf(a[i], bv.x, a2[i][0]);
                a2[i][1] = fmaf(a[i], bv.y, a2[i][1]);
            }
        }
#pragma unroll
        for (int i = 0; i < 8; ++i) {
            const int c = tc5 * 8 + i;
            float wv = wmu[c];
            float2 o = make_float2(a2[i][0] - wv, a2[i][1] - wv);
            *(float2*)(ob + (size_t)c * M_ + m0 + tm5 * 2) = o;
        }
    }
}

extern "C" void kernel_launch(void* const* d_in, const int* in_sizes, int n_in,
                              void* d_out, int out_size, void* d_ws, size_t ws_size,
                              hipStream_t stream) {
    const float* x = (const float*)d_in[0];
    float* out = (float*)d_out;
    k_fused<<<dim3(B_), 256, 0, stream>>>(x, out);
}